// Round 1
// baseline (248.391 us; speedup 1.0000x reference)
//
#include <hip/hip_runtime.h>
#include <hip/hip_bf16.h>

// NT-Xent loss, MI355X. B=4096, C=512, N=8192, tau=0.1.
// ws layout: [0, 8MB) = bf16 normalized Z (ushort[8192*512]);
//            [8MB, 8MB+32KB) = float rowsum[8192].

#define BDIM 4096
#define CDIM 512
#define NROWS 8192

typedef __attribute__((ext_vector_type(4))) float f32x4;
typedef __attribute__((ext_vector_type(8))) short bf16x8;

__device__ __forceinline__ unsigned short f2bf_rne(float x) {
    unsigned u = __float_as_uint(x);
    u += 0x7fffu + ((u >> 16) & 1u);
    return (unsigned short)(u >> 16);
}

// ---------------- kernel 1: L2-normalize rows, emit bf16 ----------------
// 4 waves/block, one row per wave. grid = 8192/4 = 2048.
__global__ __launch_bounds__(256) void normalize_kernel(
    const float* __restrict__ z1, const float* __restrict__ z2,
    unsigned short* __restrict__ zb) {
    const int w = threadIdx.x >> 6, lane = threadIdx.x & 63;
    const int row = blockIdx.x * 4 + w;
    const float* src = (row < BDIM) ? (z1 + (size_t)row * CDIM)
                                    : (z2 + (size_t)(row - BDIM) * CDIM);
    const float4* p = (const float4*)src;
    float4 v0 = p[lane];
    float4 v1 = p[64 + lane];
    float ss = v0.x * v0.x + v0.y * v0.y + v0.z * v0.z + v0.w * v0.w +
               v1.x * v1.x + v1.y * v1.y + v1.z * v1.z + v1.w * v1.w;
#pragma unroll
    for (int m = 1; m < 64; m <<= 1) ss += __shfl_xor(ss, m, 64);
    const float s = 1.0f / fmaxf(sqrtf(ss), 1e-12f);
    ushort4 o0, o1;
    o0.x = f2bf_rne(v0.x * s); o0.y = f2bf_rne(v0.y * s);
    o0.z = f2bf_rne(v0.z * s); o0.w = f2bf_rne(v0.w * s);
    o1.x = f2bf_rne(v1.x * s); o1.y = f2bf_rne(v1.y * s);
    o1.z = f2bf_rne(v1.z * s); o1.w = f2bf_rne(v1.w * s);
    ushort4* q = (ushort4*)(zb + (size_t)row * CDIM);
    q[lane] = o0;
    q[64 + lane] = o1;
}

// ---------------- kernel 2: fused exp(Z Z^T / tau) row-sums ----------------
// m97 structure: 128x128 tile, BK=64, global_load_lds w=16, 16x16x32 bf16 MFMA.
// 4 waves arranged 2x2 (each wave 64x64). grid = (64, 64).
__global__ __launch_bounds__(256) void simgemm_kernel(
    const unsigned short* __restrict__ Z, float* __restrict__ rowsum) {
    __shared__ unsigned short Alds[128 * 64];  // 16 KB, row-major [128][64]
    __shared__ unsigned short Blds[128 * 64];  // 16 KB

    const int t = threadIdx.x;
    const int lane = t & 63, w = t >> 6;
    const int wr = w >> 1, wc = w & 1;
    const int by = blockIdx.y, bx = blockIdx.x;

    f32x4 acc[4][4] = {};

    // staging geometry: issue i covers rows [i*32, i*32+32), thread t -> row t>>3, colbytes (t&7)*16
    const int srow = t >> 3;            // 0..31
    const int scolb = (t & 7) << 4;     // 0..112 bytes
    const char* Zb = (const char*)Z;

    for (int k0 = 0; k0 < CDIM; k0 += 64) {
#pragma unroll
        for (int i = 0; i < 4; ++i) {
            const char* ga = Zb + ((size_t)(by * 128 + i * 32 + srow) << 10) + (k0 << 1) + scolb;
            __builtin_amdgcn_global_load_lds(
                (const __attribute__((address_space(1))) void*)ga,
                (__attribute__((address_space(3))) void*)(Alds + i * 2048 + w * 512),
                16, 0, 0);
        }
#pragma unroll
        for (int i = 0; i < 4; ++i) {
            const char* gb = Zb + ((size_t)(bx * 128 + i * 32 + srow) << 10) + (k0 << 1) + scolb;
            __builtin_amdgcn_global_load_lds(
                (const __attribute__((address_space(1))) void*)gb,
                (__attribute__((address_space(3))) void*)(Blds + i * 2048 + w * 512),
                16, 0, 0);
        }
        __syncthreads();  // compiler drains vmcnt before barrier

#pragma unroll
        for (int kk = 0; kk < 2; ++kk) {
            const int koff = ((lane >> 4) << 4) + kk * 64;  // byte offset in 128B row
            bf16x8 af[4], bfr[4];
#pragma unroll
            for (int mi = 0; mi < 4; ++mi) {
                const int row = wr * 64 + mi * 16 + (lane & 15);
                af[mi] = *(const bf16x8*)((const char*)Alds + row * 128 + koff);
            }
#pragma unroll
            for (int ni = 0; ni < 4; ++ni) {
                const int row = wc * 64 + ni * 16 + (lane & 15);
                bfr[ni] = *(const bf16x8*)((const char*)Blds + row * 128 + koff);
            }
#pragma unroll
            for (int mi = 0; mi < 4; ++mi)
#pragma unroll
                for (int ni = 0; ni < 4; ++ni)
                    acc[mi][ni] = __builtin_amdgcn_mfma_f32_16x16x32_bf16(
                        af[mi], bfr[ni], acc[mi][ni], 0, 0, 0);
        }
        __syncthreads();  // all waves done reading before next-tile overwrite
    }

    // epilogue: exp + row-sum.  C/D: col=lane&15, row=(lane>>4)*4+j
    const float SC = 14.4269504088896340736f;  // log2(e)/tau
    const int g = lane >> 4;
#pragma unroll
    for (int mi = 0; mi < 4; ++mi) {
        float rs0 = 0.f, rs1 = 0.f, rs2 = 0.f, rs3 = 0.f;
#pragma unroll
        for (int ni = 0; ni < 4; ++ni) {
            f32x4 a = acc[mi][ni];
            rs0 += exp2f(a[0] * SC);
            rs1 += exp2f(a[1] * SC);
            rs2 += exp2f(a[2] * SC);
            rs3 += exp2f(a[3] * SC);
        }
#pragma unroll
        for (int m = 1; m < 16; m <<= 1) {
            rs0 += __shfl_xor(rs0, m, 64);
            rs1 += __shfl_xor(rs1, m, 64);
            rs2 += __shfl_xor(rs2, m, 64);
            rs3 += __shfl_xor(rs3, m, 64);
        }
        if ((lane & 15) == 0) {
            const int rbase = by * 128 + wr * 64 + mi * 16 + g * 4;
            atomicAdd(&rowsum[rbase + 0], rs0);
            atomicAdd(&rowsum[rbase + 1], rs1);
            atomicAdd(&rowsum[rbase + 2], rs2);
            atomicAdd(&rowsum[rbase + 3], rs3);
        }
    }
}

// ---------------- kernel 3: exact fp32 positive + loss reduce ----------------
// 4 waves/block, 4 pairs/wave. grid = 4096/16 = 256.
__global__ __launch_bounds__(256) void finalize_kernel(
    const float* __restrict__ z1, const float* __restrict__ z2,
    const float* __restrict__ rowsum, float* __restrict__ out) {
    __shared__ float sm[4];
    const int w = threadIdx.x >> 6, lane = threadIdx.x & 63;
    float wsum = 0.f;
#pragma unroll
    for (int q = 0; q < 4; ++q) {
        const int r = blockIdx.x * 16 + w * 4 + q;
        const float4* p1 = (const float4*)(z1 + (size_t)r * CDIM);
        const float4* p2 = (const float4*)(z2 + (size_t)r * CDIM);
        float4 a0 = p1[lane], a1 = p1[64 + lane];
        float4 b0 = p2[lane], b1 = p2[64 + lane];
        float s1 = a0.x * a0.x + a0.y * a0.y + a0.z * a0.z + a0.w * a0.w +
                   a1.x * a1.x + a1.y * a1.y + a1.z * a1.z + a1.w * a1.w;
        float s2 = b0.x * b0.x + b0.y * b0.y + b0.z * b0.z + b0.w * b0.w +
                   b1.x * b1.x + b1.y * b1.y + b1.z * b1.z + b1.w * b1.w;
        float d = a0.x * b0.x + a0.y * b0.y + a0.z * b0.z + a0.w * b0.w +
                  a1.x * b1.x + a1.y * b1.y + a1.z * b1.z + a1.w * b1.w;
#pragma unroll
        for (int m = 1; m < 64; m <<= 1) {
            s1 += __shfl_xor(s1, m, 64);
            s2 += __shfl_xor(s2, m, 64);
            d += __shfl_xor(d, m, 64);
        }
        if (lane == 0) {
            const float n1 = fmaxf(sqrtf(s1), 1e-12f);
            const float n2 = fmaxf(sqrtf(s2), 1e-12f);
            const float p10 = (d / (n1 * n2)) * 10.0f;  // pos_dot / tau
            const float pos = expf(p10);
            const float pl = (logf(rowsum[r] - pos) - p10) +
                             (logf(rowsum[r + BDIM] - pos) - p10);
            wsum += pl;
        }
    }
    if (lane == 0) sm[w] = wsum;
    __syncthreads();
    if (threadIdx.x == 0) {
        const float tot = sm[0] + sm[1] + sm[2] + sm[3];
        atomicAdd(out, tot * (1.0f / ((float)NROWS * (float)BDIM)));
    }
}

extern "C" void kernel_launch(void* const* d_in, const int* in_sizes, int n_in,
                              void* d_out, int out_size, void* d_ws, size_t ws_size,
                              hipStream_t stream) {
    const float* z1 = (const float*)d_in[0];
    const float* z2 = (const float*)d_in[1];
    float* out = (float*)d_out;
    unsigned short* zb = (unsigned short*)d_ws;
    float* rowsum = (float*)((char*)d_ws + (size_t)NROWS * CDIM * 2);

    hipMemsetAsync(rowsum, 0, NROWS * sizeof(float), stream);
    hipMemsetAsync(out, 0, sizeof(float), stream);

    normalize_kernel<<<NROWS / 4, 256, 0, stream>>>(z1, z2, zb);
    dim3 g2(64, 64);
    simgemm_kernel<<<g2, 256, 0, stream>>>(zb, rowsum);
    finalize_kernel<<<BDIM / 16, 256, 0, stream>>>(z1, z2, rowsum, out);
}

// Round 3
// 162.435 us; speedup vs baseline: 1.5292x; 1.5292x over previous
//
#include <hip/hip_runtime.h>
#include <hip/hip_bf16.h>

// NT-Xent loss, MI355X. B=4096, C=512, N=8192, tau=0.1.
// ws layout: [0, 8MB)            bf16 normalized Z (ushort[8192*512])
//            [8MB, 8MB+32KB)     float rowsum[8192]
//            [8MB+32KB, +16KB)   float pos10[4096]  (pos_dot/tau, exact fp32)

#define BDIM 4096
#define CDIM 512
#define NROWS 8192

typedef __attribute__((ext_vector_type(4))) float f32x4;
typedef __attribute__((ext_vector_type(8))) short bf16x8;

__device__ __forceinline__ unsigned short f2bf_rne(float x) {
    unsigned u = __float_as_uint(x);
    u += 0x7fffu + ((u >> 16) & 1u);
    return (unsigned short)(u >> 16);
}

// ------- kernel 1: L2-normalize rows -> bf16, fused exact positive dot -------
// 4 waves/block, one PAIR (z1[r], z2[r]) per wave. grid = 4096/4 = 1024.
__global__ __launch_bounds__(256) void normalize_kernel(
    const float* __restrict__ z1, const float* __restrict__ z2,
    unsigned short* __restrict__ zb, float* __restrict__ pos10) {
    const int w = threadIdx.x >> 6, lane = threadIdx.x & 63;
    const int r = blockIdx.x * 4 + w;  // pair index 0..4095
    const float4* p1 = (const float4*)(z1 + (size_t)r * CDIM);
    const float4* p2 = (const float4*)(z2 + (size_t)r * CDIM);
    float4 a0 = p1[lane], a1 = p1[64 + lane];
    float4 b0 = p2[lane], b1 = p2[64 + lane];
    float s1 = a0.x * a0.x + a0.y * a0.y + a0.z * a0.z + a0.w * a0.w +
               a1.x * a1.x + a1.y * a1.y + a1.z * a1.z + a1.w * a1.w;
    float s2 = b0.x * b0.x + b0.y * b0.y + b0.z * b0.z + b0.w * b0.w +
               b1.x * b1.x + b1.y * b1.y + b1.z * b1.z + b1.w * b1.w;
    float d = a0.x * b0.x + a0.y * b0.y + a0.z * b0.z + a0.w * b0.w +
              a1.x * b1.x + a1.y * b1.y + a1.z * b1.z + a1.w * b1.w;
#pragma unroll
    for (int m = 1; m < 64; m <<= 1) {
        s1 += __shfl_xor(s1, m, 64);
        s2 += __shfl_xor(s2, m, 64);
        d += __shfl_xor(d, m, 64);
    }
    const float n1 = fmaxf(sqrtf(s1), 1e-12f);
    const float n2 = fmaxf(sqrtf(s2), 1e-12f);
    const float i1 = 1.0f / n1, i2 = 1.0f / n2;
    ushort4 o;
    ushort4* q1 = (ushort4*)(zb + (size_t)r * CDIM);
    ushort4* q2 = (ushort4*)(zb + (size_t)(r + BDIM) * CDIM);
    o.x = f2bf_rne(a0.x * i1); o.y = f2bf_rne(a0.y * i1);
    o.z = f2bf_rne(a0.z * i1); o.w = f2bf_rne(a0.w * i1);
    q1[lane] = o;
    o.x = f2bf_rne(a1.x * i1); o.y = f2bf_rne(a1.y * i1);
    o.z = f2bf_rne(a1.z * i1); o.w = f2bf_rne(a1.w * i1);
    q1[64 + lane] = o;
    o.x = f2bf_rne(b0.x * i2); o.y = f2bf_rne(b0.y * i2);
    o.z = f2bf_rne(b0.z * i2); o.w = f2bf_rne(b0.w * i2);
    q2[lane] = o;
    o.x = f2bf_rne(b1.x * i2); o.y = f2bf_rne(b1.y * i2);
    o.z = f2bf_rne(b1.z * i2); o.w = f2bf_rne(b1.w * i2);
    q2[64 + lane] = o;
    if (lane == 0) pos10[r] = (d / (n1 * n2)) * 10.0f;
}

// ------- kernel 2: triangular fused exp(Z Z^T / tau) row+col sums -------
// 128x128 tile, BK=64, global_load_lds w=16, 16x16x32 bf16 MFMA, 2x2 waves.
// Only bx >= by tiles computed; off-diagonal tiles emit row sums (by side)
// AND col sums (bx side). LDS XOR-swizzled both-sides (rule #21):
// source col pre-swizzled, ds_read col swizzled, LDS dest linear.
__global__ __launch_bounds__(256) void simgemm_kernel(
    const unsigned short* __restrict__ Z, float* __restrict__ rowsum) {
    const int bx = blockIdx.x, by = blockIdx.y;
    if (bx < by) return;
    const bool diag = (bx == by);

    __shared__ unsigned short Alds[128 * 64];  // 16 KB, [128 rows][128 B]
    __shared__ unsigned short Blds[128 * 64];  // 16 KB

    const int t = threadIdx.x;
    const int lane = t & 63, w = t >> 6;
    const int wr = w >> 1, wc = w & 1;

    f32x4 acc[4][4] = {};

    // staging: issue i covers rows [i*32, i*32+32); thread t -> row t>>3.
    // swizzle: LDS pos (row, cb) must hold global (row, cb ^ ((row&7)<<4)).
    const int srow = t >> 3;                                   // 0..31
    const int scolb = (((t & 7) ^ ((t >> 3) & 7)) << 4);       // swizzled src col
    const char* Zb = (const char*)Z;

    for (int k0 = 0; k0 < CDIM; k0 += 64) {
#pragma unroll
        for (int i = 0; i < 4; ++i) {
            const char* ga = Zb + ((size_t)(by * 128 + i * 32 + srow) << 10) + (k0 << 1) + scolb;
            __builtin_amdgcn_global_load_lds(
                (const __attribute__((address_space(1))) void*)ga,
                (__attribute__((address_space(3))) void*)(Alds + i * 2048 + w * 512),
                16, 0, 0);
        }
#pragma unroll
        for (int i = 0; i < 4; ++i) {
            const char* gb = Zb + ((size_t)(bx * 128 + i * 32 + srow) << 10) + (k0 << 1) + scolb;
            __builtin_amdgcn_global_load_lds(
                (const __attribute__((address_space(1))) void*)gb,
                (__attribute__((address_space(3))) void*)(Blds + i * 2048 + w * 512),
                16, 0, 0);
        }
        __syncthreads();

        const int sw = (lane & 7) << 4;  // fragment rows all have row&7 == lane&7
#pragma unroll
        for (int kk = 0; kk < 2; ++kk) {
            const int koff = (((lane >> 4) << 4) + kk * 64) ^ sw;
            bf16x8 af[4], bfr[4];
#pragma unroll
            for (int mi = 0; mi < 4; ++mi) {
                const int row = wr * 64 + mi * 16 + (lane & 15);
                af[mi] = *(const bf16x8*)((const char*)Alds + row * 128 + koff);
            }
#pragma unroll
            for (int ni = 0; ni < 4; ++ni) {
                const int row = wc * 64 + ni * 16 + (lane & 15);
                bfr[ni] = *(const bf16x8*)((const char*)Blds + row * 128 + koff);
            }
#pragma unroll
            for (int mi = 0; mi < 4; ++mi)
#pragma unroll
                for (int ni = 0; ni < 4; ++ni)
                    acc[mi][ni] = __builtin_amdgcn_mfma_f32_16x16x32_bf16(
                        af[mi], bfr[ni], acc[mi][ni], 0, 0, 0);
        }
        __syncthreads();
    }

    // epilogue. C/D (verified): row = wr*64+mi*16+(lane>>4)*4+j, col = wc*64+ni*16+(lane&15)
    const float SC = 14.4269504088896340736f;  // log2(e)/tau
    const int g = lane >> 4;
    float cs[4] = {0.f, 0.f, 0.f, 0.f};  // per-ni column sums
#pragma unroll
    for (int mi = 0; mi < 4; ++mi) {
        float rs0 = 0.f, rs1 = 0.f, rs2 = 0.f, rs3 = 0.f;
#pragma unroll
        for (int ni = 0; ni < 4; ++ni) {
            f32x4 a = acc[mi][ni];
            const float e0 = exp2f(a[0] * SC);
            const float e1 = exp2f(a[1] * SC);
            const float e2 = exp2f(a[2] * SC);
            const float e3 = exp2f(a[3] * SC);
            rs0 += e0; rs1 += e1; rs2 += e2; rs3 += e3;
            cs[ni] += (e0 + e1) + (e2 + e3);
        }
#pragma unroll
        for (int m = 1; m < 16; m <<= 1) {
            rs0 += __shfl_xor(rs0, m, 64);
            rs1 += __shfl_xor(rs1, m, 64);
            rs2 += __shfl_xor(rs2, m, 64);
            rs3 += __shfl_xor(rs3, m, 64);
        }
        if ((lane & 15) == 0) {
            const int rbase = by * 128 + wr * 64 + mi * 16 + g * 4;
            atomicAdd(&rowsum[rbase + 0], rs0);
            atomicAdd(&rowsum[rbase + 1], rs1);
            atomicAdd(&rowsum[rbase + 2], rs2);
            atomicAdd(&rowsum[rbase + 3], rs3);
        }
    }
    if (!diag) {
#pragma unroll
        for (int ni = 0; ni < 4; ++ni) {
            float c = cs[ni];
            c += __shfl_xor(c, 16, 64);
            c += __shfl_xor(c, 32, 64);
            if (lane < 16)
                atomicAdd(&rowsum[bx * 128 + wc * 64 + ni * 16 + lane], c);
        }
    }
}

// ------- kernel 3: per-pair loss from rowsum + pos10, reduce to scalar -------
// grid = 16 blocks x 256 threads, one pair per thread.
__global__ __launch_bounds__(256) void finalize_kernel(
    const float* __restrict__ rowsum, const float* __restrict__ pos10,
    float* __restrict__ out) {
    __shared__ float sm[4];
    const int w = threadIdx.x >> 6, lane = threadIdx.x & 63;
    const int r = blockIdx.x * 256 + threadIdx.x;  // 0..4095
    const float p10 = pos10[r];
    const float pos = expf(p10);
    float l = (logf(rowsum[r] - pos) - p10) +
              (logf(rowsum[r + BDIM] - pos) - p10);
#pragma unroll
    for (int m = 1; m < 64; m <<= 1) l += __shfl_xor(l, m, 64);
    if (lane == 0) sm[w] = l;
    __syncthreads();
    if (threadIdx.x == 0) {
        const float tot = sm[0] + sm[1] + sm[2] + sm[3];
        atomicAdd(out, tot * (1.0f / ((float)NROWS * (float)BDIM)));
    }
}

extern "C" void kernel_launch(void* const* d_in, const int* in_sizes, int n_in,
                              void* d_out, int out_size, void* d_ws, size_t ws_size,
                              hipStream_t stream) {
    const float* z1 = (const float*)d_in[0];
    const float* z2 = (const float*)d_in[1];
    float* out = (float*)d_out;
    unsigned short* zb = (unsigned short*)d_ws;
    float* rowsum = (float*)((char*)d_ws + (size_t)NROWS * CDIM * 2);
    float* pos10 = rowsum + NROWS;

    hipMemsetAsync(rowsum, 0, NROWS * sizeof(float), stream);
    hipMemsetAsync(out, 0, sizeof(float), stream);

    normalize_kernel<<<BDIM / 4, 256, 0, stream>>>(z1, z2, zb, pos10);
    dim3 g2(64, 64);
    simgemm_kernel<<<g2, 256, 0, stream>>>(zb, rowsum);
    finalize_kernel<<<BDIM / 256, 256, 0, stream>>>(rowsum, pos10, out);
}

// Round 4
// 154.769 us; speedup vs baseline: 1.6049x; 1.0495x over previous
//
#include <hip/hip_runtime.h>
#include <hip/hip_bf16.h>

// NT-Xent loss, MI355X. B=4096, C=512, N=8192, tau=0.1.
// ws layout: [0, 8MB)            bf16 normalized Z (ushort[8192*512])
//            [8MB, 8MB+32KB)     float rowsum[8192]
//            [8MB+32KB, +16KB)   float pos10[4096]  (pos_dot/tau, exact fp32)

#define BDIM 4096
#define CDIM 512
#define NROWS 8192

typedef __attribute__((ext_vector_type(4))) float f32x4;
typedef __attribute__((ext_vector_type(8))) short bf16x8;

__device__ __forceinline__ unsigned short f2bf_rne(float x) {
    unsigned u = __float_as_uint(x);
    u += 0x7fffu + ((u >> 16) & 1u);
    return (unsigned short)(u >> 16);
}

// ------- kernel 1: L2-normalize rows -> bf16, fused exact positive dot -------
__global__ __launch_bounds__(256) void normalize_kernel(
    const float* __restrict__ z1, const float* __restrict__ z2,
    unsigned short* __restrict__ zb, float* __restrict__ pos10) {
    const int w = threadIdx.x >> 6, lane = threadIdx.x & 63;
    const int r = blockIdx.x * 4 + w;  // pair index 0..4095
    const float4* p1 = (const float4*)(z1 + (size_t)r * CDIM);
    const float4* p2 = (const float4*)(z2 + (size_t)r * CDIM);
    float4 a0 = p1[lane], a1 = p1[64 + lane];
    float4 b0 = p2[lane], b1 = p2[64 + lane];
    float s1 = a0.x * a0.x + a0.y * a0.y + a0.z * a0.z + a0.w * a0.w +
               a1.x * a1.x + a1.y * a1.y + a1.z * a1.z + a1.w * a1.w;
    float s2 = b0.x * b0.x + b0.y * b0.y + b0.z * b0.z + b0.w * b0.w +
               b1.x * b1.x + b1.y * b1.y + b1.z * b1.z + b1.w * b1.w;
    float d = a0.x * b0.x + a0.y * b0.y + a0.z * b0.z + a0.w * b0.w +
              a1.x * b1.x + a1.y * b1.y + a1.z * b1.z + a1.w * b1.w;
#pragma unroll
    for (int m = 1; m < 64; m <<= 1) {
        s1 += __shfl_xor(s1, m, 64);
        s2 += __shfl_xor(s2, m, 64);
        d += __shfl_xor(d, m, 64);
    }
    const float n1 = fmaxf(sqrtf(s1), 1e-12f);
    const float n2 = fmaxf(sqrtf(s2), 1e-12f);
    const float i1 = 1.0f / n1, i2 = 1.0f / n2;
    ushort4 o;
    ushort4* q1 = (ushort4*)(zb + (size_t)r * CDIM);
    ushort4* q2 = (ushort4*)(zb + (size_t)(r + BDIM) * CDIM);
    o.x = f2bf_rne(a0.x * i1); o.y = f2bf_rne(a0.y * i1);
    o.z = f2bf_rne(a0.z * i1); o.w = f2bf_rne(a0.w * i1);
    q1[lane] = o;
    o.x = f2bf_rne(a1.x * i1); o.y = f2bf_rne(a1.y * i1);
    o.z = f2bf_rne(a1.z * i1); o.w = f2bf_rne(a1.w * i1);
    q1[64 + lane] = o;
    o.x = f2bf_rne(b0.x * i2); o.y = f2bf_rne(b0.y * i2);
    o.z = f2bf_rne(b0.z * i2); o.w = f2bf_rne(b0.w * i2);
    q2[lane] = o;
    o.x = f2bf_rne(b1.x * i2); o.y = f2bf_rne(b1.y * i2);
    o.z = f2bf_rne(b1.z * i2); o.w = f2bf_rne(b1.w * i2);
    q2[64 + lane] = o;
    if (lane == 0) pos10[r] = (d / (n1 * n2)) * 10.0f;
}

// ------- kernel 2: triangular fused exp(Z Z^T / tau) row+col sums -------
// 128x128 tile, BK=64, DOUBLE-BUFFERED 2-phase (stage t+1 before compute t,
// one compiler-drained barrier per iter), global_load_lds w=16, st-swizzled
// LDS (both-sides, rule #21), 16x16x32 bf16 MFMA, 2x2 waves. bx>=by only.
__global__ __launch_bounds__(256) void simgemm_kernel(
    const unsigned short* __restrict__ Z, float* __restrict__ rowsum) {
    const int bx = blockIdx.x, by = blockIdx.y;
    if (bx < by) return;
    const bool diag = (bx == by);

    // [A0, B0, A1, B1] each [128 rows][128 B], 64 KB total -> 2 blocks/CU
    __shared__ unsigned short lds[4][128 * 64];

    const int t = threadIdx.x;
    const int lane = t & 63, w = t >> 6;
    const int wr = w >> 1, wc = w & 1;

    f32x4 acc[4][4] = {};

    // staging: issue i covers rows [i*32, i*32+32); thread t -> row t>>3.
    // swizzle: LDS pos (row, cb) holds global (row, cb ^ ((row&7)<<4)).
    const int srow = t >> 3;                              // 0..31
    const int scolb = (((t & 7) ^ ((t >> 3) & 7)) << 4);  // swizzled src col
    const char* Zb = (const char*)Z;
    const size_t apan = ((size_t)(by * 128) << 10);
    const size_t bpan = ((size_t)(bx * 128) << 10);

#define STAGE(k0, db)                                                          \
    {                                                                          \
        const int kb_ = ((k0) << 1) + scolb;                                   \
        _Pragma("unroll") for (int i_ = 0; i_ < 4; ++i_) {                     \
            const size_t ro_ = ((size_t)(i_ * 32 + srow) << 10) + kb_;         \
            __builtin_amdgcn_global_load_lds(                                  \
                (const __attribute__((address_space(1))) void*)(Zb + apan + ro_), \
                (__attribute__((address_space(3))) void*)(lds[(db) * 2] + i_ * 2048 + w * 512), \
                16, 0, 0);                                                     \
            __builtin_amdgcn_global_load_lds(                                  \
                (const __attribute__((address_space(1))) void*)(Zb + bpan + ro_), \
                (__attribute__((address_space(3))) void*)(lds[(db) * 2 + 1] + i_ * 2048 + w * 512), \
                16, 0, 0);                                                     \
        }                                                                      \
    }

    STAGE(0, 0);
    __syncthreads();  // vmcnt(0) drain: tile 0 resident

    const int sw = (lane & 7) << 4;  // fragment rows have row&7 == lane&7
#pragma unroll
    for (int it = 0; it < 8; ++it) {
        const int cur = it & 1;
        if (it < 7) STAGE((it + 1) * 64, cur ^ 1);  // prefetch overlaps compute

        const unsigned short* Ab = lds[cur * 2];
        const unsigned short* Bb = lds[cur * 2 + 1];
#pragma unroll
        for (int kk = 0; kk < 2; ++kk) {
            const int koff = (((lane >> 4) << 4) + kk * 64) ^ sw;
            bf16x8 af[4], bfr[4];
#pragma unroll
            for (int mi = 0; mi < 4; ++mi) {
                const int row = wr * 64 + mi * 16 + (lane & 15);
                af[mi] = *(const bf16x8*)((const char*)Ab + row * 128 + koff);
            }
#pragma unroll
            for (int ni = 0; ni < 4; ++ni) {
                const int row = wc * 64 + ni * 16 + (lane & 15);
                bfr[ni] = *(const bf16x8*)((const char*)Bb + row * 128 + koff);
            }
#pragma unroll
            for (int mi = 0; mi < 4; ++mi)
#pragma unroll
                for (int ni = 0; ni < 4; ++ni)
                    acc[mi][ni] = __builtin_amdgcn_mfma_f32_16x16x32_bf16(
                        af[mi], bfr[ni], acc[mi][ni], 0, 0, 0);
        }
        // drains this iter's prefetch (vmcnt(0)) + guards buffer swap
        __syncthreads();
    }
#undef STAGE

    // epilogue. C/D (verified): row = wr*64+mi*16+(lane>>4)*4+j, col = wc*64+ni*16+(lane&15)
    const float SC = 14.4269504088896340736f;  // log2(e)/tau
    const int g = lane >> 4;
    float cs[4] = {0.f, 0.f, 0.f, 0.f};  // per-ni column sums
#pragma unroll
    for (int mi = 0; mi < 4; ++mi) {
        float rs0 = 0.f, rs1 = 0.f, rs2 = 0.f, rs3 = 0.f;
#pragma unroll
        for (int ni = 0; ni < 4; ++ni) {
            f32x4 a = acc[mi][ni];
            const float e0 = exp2f(a[0] * SC);
            const float e1 = exp2f(a[1] * SC);
            const float e2 = exp2f(a[2] * SC);
            const float e3 = exp2f(a[3] * SC);
            rs0 += e0; rs1 += e1; rs2 += e2; rs3 += e3;
            cs[ni] += (e0 + e1) + (e2 + e3);
        }
#pragma unroll
        for (int m = 1; m < 16; m <<= 1) {
            rs0 += __shfl_xor(rs0, m, 64);
            rs1 += __shfl_xor(rs1, m, 64);
            rs2 += __shfl_xor(rs2, m, 64);
            rs3 += __shfl_xor(rs3, m, 64);
        }
        if ((lane & 15) == 0) {
            const int rbase = by * 128 + wr * 64 + mi * 16 + g * 4;
            atomicAdd(&rowsum[rbase + 0], rs0);
            atomicAdd(&rowsum[rbase + 1], rs1);
            atomicAdd(&rowsum[rbase + 2], rs2);
            atomicAdd(&rowsum[rbase + 3], rs3);
        }
    }
    if (!diag) {
#pragma unroll
        for (int ni = 0; ni < 4; ++ni) {
            float c = cs[ni];
            c += __shfl_xor(c, 16, 64);
            c += __shfl_xor(c, 32, 64);
            if (lane < 16)
                atomicAdd(&rowsum[bx * 128 + wc * 64 + ni * 16 + lane], c);
        }
    }
}

// ------- kernel 3: per-pair loss from rowsum + pos10, reduce to scalar -------
__global__ __launch_bounds__(256) void finalize_kernel(
    const float* __restrict__ rowsum, const float* __restrict__ pos10,
    float* __restrict__ out) {
    __shared__ float sm[4];
    const int w = threadIdx.x >> 6, lane = threadIdx.x & 63;
    const int r = blockIdx.x * 256 + threadIdx.x;  // 0..4095
    const float p10 = pos10[r];
    const float pos = expf(p10);
    float l = (logf(rowsum[r] - pos) - p10) +
              (logf(rowsum[r + BDIM] - pos) - p10);
#pragma unroll
    for (int m = 1; m < 64; m <<= 1) l += __shfl_xor(l, m, 64);
    if (lane == 0) sm[w] = l;
    __syncthreads();
    if (threadIdx.x == 0) {
        const float tot = sm[0] + sm[1] + sm[2] + sm[3];
        atomicAdd(out, tot * (1.0f / ((float)NROWS * (float)BDIM)));
    }
}

extern "C" void kernel_launch(void* const* d_in, const int* in_sizes, int n_in,
                              void* d_out, int out_size, void* d_ws, size_t ws_size,
                              hipStream_t stream) {
    const float* z1 = (const float*)d_in[0];
    const float* z2 = (const float*)d_in[1];
    float* out = (float*)d_out;
    unsigned short* zb = (unsigned short*)d_ws;
    float* rowsum = (float*)((char*)d_ws + (size_t)NROWS * CDIM * 2);
    float* pos10 = rowsum + NROWS;

    hipMemsetAsync(rowsum, 0, NROWS * sizeof(float), stream);
    hipMemsetAsync(out, 0, sizeof(float), stream);

    normalize_kernel<<<BDIM / 4, 256, 0, stream>>>(z1, z2, zb, pos10);
    dim3 g2(64, 64);
    simgemm_kernel<<<g2, 256, 0, stream>>>(zb, rowsum);
    finalize_kernel<<<BDIM / 256, 256, 0, stream>>>(rowsum, pos10, out);
}

// Round 5
// 142.040 us; speedup vs baseline: 1.7487x; 1.0896x over previous
//
#include <hip/hip_runtime.h>
#include <hip/hip_bf16.h>

// NT-Xent loss, MI355X. B=4096, C=512, N=8192, tau=0.1.
// ws layout: [0, 8MB)            bf16 normalized Z (ushort[8192*512])
//            [8MB, 8MB+32KB)     float rowsum[8192]
//            [8MB+32KB, +16KB)   float pos10[4096]  (pos_dot/tau, exact fp32)

#define BDIM 4096
#define CDIM 512
#define NROWS 8192
#define NTILE 32   // 8192 / 256
#define NBLK 528   // NTILE*(NTILE+1)/2 triangular tiles

typedef __attribute__((ext_vector_type(4))) float f32x4;
typedef __attribute__((ext_vector_type(8))) short bf16x8;

__device__ __forceinline__ unsigned short f2bf_rne(float x) {
    unsigned u = __float_as_uint(x);
    u += 0x7fffu + ((u >> 16) & 1u);
    return (unsigned short)(u >> 16);
}

// ------- kernel 1: L2-normalize -> bf16, exact positive dot, zero rowsum/out -------
// 4 waves/block, one PAIR (z1[r], z2[r]) per wave. grid = 4096/4 = 1024.
__global__ __launch_bounds__(256) void normalize_kernel(
    const float* __restrict__ z1, const float* __restrict__ z2,
    unsigned short* __restrict__ zb, float* __restrict__ pos10,
    float* __restrict__ rowsum, float* __restrict__ out) {
    if (blockIdx.x == 0) {  // fused zero-init (stream order makes it visible to k2/k3)
#pragma unroll
        for (int i = 0; i < NROWS / 256; ++i) rowsum[i * 256 + threadIdx.x] = 0.f;
        if (threadIdx.x == 0) out[0] = 0.f;
    }
    const int w = threadIdx.x >> 6, lane = threadIdx.x & 63;
    const int r = blockIdx.x * 4 + w;  // pair index 0..4095
    const float4* p1 = (const float4*)(z1 + (size_t)r * CDIM);
    const float4* p2 = (const float4*)(z2 + (size_t)r * CDIM);
    float4 a0 = p1[lane], a1 = p1[64 + lane];
    float4 b0 = p2[lane], b1 = p2[64 + lane];
    float s1 = a0.x * a0.x + a0.y * a0.y + a0.z * a0.z + a0.w * a0.w +
               a1.x * a1.x + a1.y * a1.y + a1.z * a1.z + a1.w * a1.w;
    float s2 = b0.x * b0.x + b0.y * b0.y + b0.z * b0.z + b0.w * b0.w +
               b1.x * b1.x + b1.y * b1.y + b1.z * b1.z + b1.w * b1.w;
    float d = a0.x * b0.x + a0.y * b0.y + a0.z * b0.z + a0.w * b0.w +
              a1.x * b1.x + a1.y * b1.y + a1.z * b1.z + a1.w * b1.w;
#pragma unroll
    for (int m = 1; m < 64; m <<= 1) {
        s1 += __shfl_xor(s1, m, 64);
        s2 += __shfl_xor(s2, m, 64);
        d += __shfl_xor(d, m, 64);
    }
    const float n1 = fmaxf(sqrtf(s1), 1e-12f);
    const float n2 = fmaxf(sqrtf(s2), 1e-12f);
    const float i1 = 1.0f / n1, i2 = 1.0f / n2;
    ushort4 o;
    ushort4* q1 = (ushort4*)(zb + (size_t)r * CDIM);
    ushort4* q2 = (ushort4*)(zb + (size_t)(r + BDIM) * CDIM);
    o.x = f2bf_rne(a0.x * i1); o.y = f2bf_rne(a0.y * i1);
    o.z = f2bf_rne(a0.z * i1); o.w = f2bf_rne(a0.w * i1);
    q1[lane] = o;
    o.x = f2bf_rne(a1.x * i1); o.y = f2bf_rne(a1.y * i1);
    o.z = f2bf_rne(a1.z * i1); o.w = f2bf_rne(a1.w * i1);
    q1[64 + lane] = o;
    o.x = f2bf_rne(b0.x * i2); o.y = f2bf_rne(b0.y * i2);
    o.z = f2bf_rne(b0.z * i2); o.w = f2bf_rne(b0.w * i2);
    q2[lane] = o;
    o.x = f2bf_rne(b1.x * i2); o.y = f2bf_rne(b1.y * i2);
    o.z = f2bf_rne(b1.z * i2); o.w = f2bf_rne(b1.w * i2);
    q2[64 + lane] = o;
    if (lane == 0) pos10[r] = (d / (n1 * n2)) * 10.0f;
}

// ------- kernel 2: triangular fused exp(Z Z^T / tau) row+col sums -------
// 256x256 tile, BK=64, 8 waves (2M x 4N), per-wave C = 128x64.
// Circular 2-buffer pipeline with COUNTED vmcnt(8) gates (never 0 in main
// loop): at iter k, after issuing tile k+1's 8 loads, vmcnt(8) retires
// exactly tile k's 8 loads (in-order vmcnt), then s_barrier publishes
// cross-wave. End-of-iter barrier = WAR guard for next iter's stage into
// the buffer just read. LDS st-swizzle both-sides (rule #21), conflicts=0.
__global__ __launch_bounds__(512, 2) void simgemm_kernel(
    const unsigned short* __restrict__ Z, float* __restrict__ rowsum) {
    // triangular 1D grid -> (by, bx) with bx >= by
    int by = 0, rem = blockIdx.x;
    while (rem >= NTILE - by) { rem -= NTILE - by; ++by; }
    const int bx = by + rem;
    const bool diag = (bx == by);

    __shared__ unsigned short lds[2][2][256 * 64];  // [buf][A/B][row*64+col] = 128 KB

    const int t = threadIdx.x;
    const int lane = t & 63, w = t >> 6;  // 8 waves
    const int wr = w >> 2, wc = w & 3;    // 2 x 4

    f32x4 acc[8][4] = {};

    // staging: pass i covers rows [i*64, i*64+64); thread t -> row t>>3, 16B col t&7.
    // swizzle: LDS (row, cb) holds global (row, cb ^ ((row&7)<<4)); row&7 == (t>>3)&7.
    const int srow = t >> 3;                              // 0..63
    const int scolb = (((t & 7) ^ ((t >> 3) & 7)) << 4);  // pre-swizzled src col byte
    const char* Zb = (const char*)Z;
    const size_t apan = ((size_t)(by * 256) << 10);
    const size_t bpan = ((size_t)(bx * 256) << 10);

#define STAGE(kt, db)                                                             \
    {                                                                             \
        const int kb_ = ((kt) << 7) + scolb;                                      \
        _Pragma("unroll") for (int i_ = 0; i_ < 4; ++i_) {                        \
            const size_t ro_ = ((size_t)(i_ * 64 + srow) << 10) + kb_;            \
            __builtin_amdgcn_global_load_lds(                                     \
                (const __attribute__((address_space(1))) void*)(Zb + apan + ro_), \
                (__attribute__((address_space(3))) void*)((char*)&lds[db][0][0] + i_ * 8192 + w * 1024), \
                16, 0, 0);                                                        \
            __builtin_amdgcn_global_load_lds(                                     \
                (const __attribute__((address_space(1))) void*)(Zb + bpan + ro_), \
                (__attribute__((address_space(3))) void*)((char*)&lds[db][1][0] + i_ * 8192 + w * 1024), \
                16, 0, 0);                                                        \
        }                                                                         \
    }

    STAGE(0, 0);
    asm volatile("s_waitcnt vmcnt(0)\n\ts_barrier" ::: "memory");  // prologue drain (once)

    const int swz = (lane & 7) << 4;  // fragment rows all have row&7 == lane&7
#pragma unroll
    for (int it = 0; it < 8; ++it) {
        const int cur = it & 1;
        if (it < 7) {
            STAGE(it + 1, cur ^ 1);  // 8 loads in flight across this iter's compute
            asm volatile("s_waitcnt vmcnt(8)\n\ts_barrier" ::: "memory");  // tile `it` resident
        } else {
            asm volatile("s_waitcnt vmcnt(0)\n\ts_barrier" ::: "memory");  // last tile
        }

        const char* Ab = (const char*)&lds[cur][0][0];
        const char* Bb = (const char*)&lds[cur][1][0];
#pragma unroll
        for (int kk = 0; kk < 2; ++kk) {
            const int koff = (kk * 64 + ((lane >> 4) << 4)) ^ swz;
            bf16x8 af[8], bfr[4];
#pragma unroll
            for (int mi = 0; mi < 8; ++mi) {
                const int row = wr * 128 + mi * 16 + (lane & 15);
                af[mi] = *(const bf16x8*)(Ab + row * 128 + koff);
            }
#pragma unroll
            for (int ni = 0; ni < 4; ++ni) {
                const int row = wc * 64 + ni * 16 + (lane & 15);
                bfr[ni] = *(const bf16x8*)(Bb + row * 128 + koff);
            }
#pragma unroll
            for (int mi = 0; mi < 8; ++mi)
#pragma unroll
                for (int ni = 0; ni < 4; ++ni)
                    acc[mi][ni] = __builtin_amdgcn_mfma_f32_16x16x32_bf16(
                        af[mi], bfr[ni], acc[mi][ni], 0, 0, 0);
        }
        // WAR guard: next iter's STAGE overwrites buf[cur]
        asm volatile("s_barrier" ::: "memory");
    }
#undef STAGE

    // epilogue. C/D: row = wr*128+mi*16+(lane>>4)*4+j, col = wc*64+ni*16+(lane&15)
    const float SC = 14.4269504088896340736f;  // log2(e)/tau
    const int g = lane >> 4;
    float cs[4] = {0.f, 0.f, 0.f, 0.f};
#pragma unroll
    for (int mi = 0; mi < 8; ++mi) {
        float rs0 = 0.f, rs1 = 0.f, rs2 = 0.f, rs3 = 0.f;
#pragma unroll
        for (int ni = 0; ni < 4; ++ni) {
            f32x4 a = acc[mi][ni];
            const float e0 = exp2f(a[0] * SC);
            const float e1 = exp2f(a[1] * SC);
            const float e2 = exp2f(a[2] * SC);
            const float e3 = exp2f(a[3] * SC);
            rs0 += e0; rs1 += e1; rs2 += e2; rs3 += e3;
            cs[ni] += (e0 + e1) + (e2 + e3);
        }
#pragma unroll
        for (int m = 1; m < 16; m <<= 1) {
            rs0 += __shfl_xor(rs0, m, 64);
            rs1 += __shfl_xor(rs1, m, 64);
            rs2 += __shfl_xor(rs2, m, 64);
            rs3 += __shfl_xor(rs3, m, 64);
        }
        if ((lane & 15) == 0) {
            const int rbase = by * 256 + wr * 128 + mi * 16 + g * 4;
            atomicAdd(&rowsum[rbase + 0], rs0);
            atomicAdd(&rowsum[rbase + 1], rs1);
            atomicAdd(&rowsum[rbase + 2], rs2);
            atomicAdd(&rowsum[rbase + 3], rs3);
        }
    }
    if (!diag) {  // symmetry: off-diagonal tile's col sums -> rows bx*256..
#pragma unroll
        for (int ni = 0; ni < 4; ++ni) {
            float c = cs[ni];
            c += __shfl_xor(c, 16, 64);
            c += __shfl_xor(c, 32, 64);
            if (lane < 16)
                atomicAdd(&rowsum[bx * 256 + wc * 64 + ni * 16 + lane], c);
        }
    }
}

// ------- kernel 3: per-pair loss from rowsum + pos10, reduce to scalar -------
__global__ __launch_bounds__(256) void finalize_kernel(
    const float* __restrict__ rowsum, const float* __restrict__ pos10,
    float* __restrict__ out) {
    __shared__ float sm[4];
    const int w = threadIdx.x >> 6, lane = threadIdx.x & 63;
    const int r = blockIdx.x * 256 + threadIdx.x;  // 0..4095
    const float p10 = pos10[r];
    const float pos = expf(p10);
    float l = (logf(rowsum[r] - pos) - p10) +
              (logf(rowsum[r + BDIM] - pos) - p10);
#pragma unroll
    for (int m = 1; m < 64; m <<= 1) l += __shfl_xor(l, m, 64);
    if (lane == 0) sm[w] = l;
    __syncthreads();
    if (threadIdx.x == 0) {
        const float tot = sm[0] + sm[1] + sm[2] + sm[3];
        atomicAdd(out, tot * (1.0f / ((float)NROWS * (float)BDIM)));
    }
}

extern "C" void kernel_launch(void* const* d_in, const int* in_sizes, int n_in,
                              void* d_out, int out_size, void* d_ws, size_t ws_size,
                              hipStream_t stream) {
    const float* z1 = (const float*)d_in[0];
    const float* z2 = (const float*)d_in[1];
    float* out = (float*)d_out;
    unsigned short* zb = (unsigned short*)d_ws;
    float* rowsum = (float*)((char*)d_ws + (size_t)NROWS * CDIM * 2);
    float* pos10 = rowsum + NROWS;

    normalize_kernel<<<BDIM / 4, 256, 0, stream>>>(z1, z2, zb, pos10, rowsum, out);
    simgemm_kernel<<<NBLK, 512, 0, stream>>>(zb, rowsum);
    finalize_kernel<<<BDIM / 256, 256, 0, stream>>>(rowsum, pos10, out);
}